// Round 5
// baseline (152.685 us; speedup 1.0000x reference)
//
#include <hip/hip_runtime.h>

typedef __bf16 bf16x8 __attribute__((ext_vector_type(8)));
typedef float  f32x4  __attribute__((ext_vector_type(4)));

#define CC 64
#define HWSZ 4096
#define CHWSZ 262144
#define NE 512
#define NPIX 131072
#define PIXB 128
#define EPS_MARGIN 0.01f

#define ET_OFF 0            // 512 codes * 256 B (hi64|lo64 bf16), XOR-swizzled rows
#define E2_OFF 131072       // 512 * 4
#define HIST_OFF 133120     // 512 * 4
#define BATCH_OFF 135168    // 32 * 4

__device__ __forceinline__ float bf2f(unsigned short u) {
    unsigned int x = ((unsigned int)u) << 16;
    return __builtin_bit_cast(float, x);
}
__device__ __forceinline__ unsigned short f2bf(float f) {
    unsigned int x = __builtin_bit_cast(unsigned int, f);
    unsigned int r = x + 0x7fffu + ((x >> 16) & 1u);
    return (unsigned short)(r >> 16);
}
__device__ __forceinline__ void gload16(const void* g, void* l) {
    __builtin_amdgcn_global_load_lds(
        (const __attribute__((address_space(1))) unsigned int*)g,
        (__attribute__((address_space(3))) unsigned int*)l, 16, 0, 0);
}

// ---- init: exact e2[512]; embed^T hi/lo [code][hi64|lo64] bf16 PRE-SWIZZLED; zero hist/batch ----
__global__ __launch_bounds__(512) void vq_init(const float* __restrict__ eg, char* __restrict__ ws) {
    __shared__ float se[CC * 513];          // stride 513 kills transpose bank conflicts
    const int tid = threadIdx.x;
    for (int i = tid; i < CC * NE; i += 512) se[(i >> 9) * 513 + (i & 511)] = eg[i];
    __syncthreads();
    float s = 0.f;
    #pragma unroll 8
    for (int k = 0; k < CC; ++k) { float v = se[k * 513 + tid]; s = __fadd_rn(s, __fmul_rn(v, v)); }
    ((float*)(ws + E2_OFF))[tid] = s;
    char* et = ws + ET_OFF;
    #pragma unroll 4
    for (int it = 0; it < 64; ++it) {
        int idx = tid + it * 512;           // word index
        int n = idx >> 6;                   // code row
        int w = idx & 63;                   // word within row
        int kk2 = w << 1;                   // element pair col
        int k = kk2 & 63;
        float v0 = se[k * 513 + n], v1 = se[(k + 1) * 513 + n];
        unsigned short c0, c1;
        if (kk2 < 64) { c0 = f2bf(v0); c1 = f2bf(v1); }
        else {
            unsigned short h0 = f2bf(v0), h1 = f2bf(v1);
            c0 = f2bf(__fsub_rn(v0, bf2f(h0)));
            c1 = f2bf(__fsub_rn(v1, bf2f(h1)));
        }
        int b = (n * 256 + w * 4) ^ ((n & 15) << 4);   // row-local XOR swizzle
        *(unsigned int*)(et + b) = (unsigned int)c0 | ((unsigned int)c1 << 16);
    }
    ((unsigned int*)(ws + HIST_OFF))[tid] = 0u;
    if (tid < 32) ((float*)(ws + BATCH_OFF))[tid] = 0.f;
}

// ---- main: split-bf16 MFMA argmin, async dbuf et staging, LDS aliased ----
__global__ __launch_bounds__(256, 4) void vq_main(const float* __restrict__ xg,
                                                  const float* __restrict__ eg,
                                                  float* __restrict__ outg,
                                                  char* __restrict__ ws) {
    __shared__ __align__(16) char sbuf[2][16384];  // phase 1: x tile [pixel][hi64|lo64]; phase 2: et dbuf
    __shared__ float e2s[NE];
    __shared__ int idxs[PIXB];
    __shared__ float wsum[4];
    __shared__ int nflag;
    __shared__ int flist[PIXB];
    __shared__ float xp[CC];
    __shared__ float redv[4];
    __shared__ int redi[4];

    const int tid  = threadIdx.x;
    const int lane = tid & 63;
    const int wv   = tid >> 6;
    const int l15  = lane & 15;
    const int l4   = lane >> 4;
    const int pix0 = blockIdx.x * PIXB;
    const int bb   = pix0 >> 12;
    const size_t xbase = (size_t)bb * CHWSZ + (pix0 & 4095);
    char* xtb = &sbuf[0][0];
    const char* etw = ws + ET_OFF;

    if (tid == 0) nflag = 0;

    // phase 1: stage x tile as bf16 hi/lo, swizzled; e2s
    {
        const int p = tid & 127, h = tid >> 7;
        const int sw = (p & 15) << 4;
        #pragma unroll
        for (int q = 0; q < 4; ++q) {
            int k0 = h * 32 + q * 8;
            float v[8];
            #pragma unroll
            for (int j = 0; j < 8; ++j) v[j] = xg[xbase + (size_t)(k0 + j) * HWSZ + p];
            unsigned int hw_[4], lw_[4];
            #pragma unroll
            for (int j = 0; j < 4; ++j) {
                unsigned short h0 = f2bf(v[2 * j]), h1 = f2bf(v[2 * j + 1]);
                unsigned short o0 = f2bf(__fsub_rn(v[2 * j], bf2f(h0)));
                unsigned short o1 = f2bf(__fsub_rn(v[2 * j + 1], bf2f(h1)));
                hw_[j] = (unsigned int)h0 | ((unsigned int)h1 << 16);
                lw_[j] = (unsigned int)o0 | ((unsigned int)o1 << 16);
            }
            *(uint4*)(xtb + ((p * 256 + 2 * k0) ^ sw)) = (uint4){hw_[0], hw_[1], hw_[2], hw_[3]};
            *(uint4*)(xtb + ((p * 256 + 128 + 2 * k0) ^ sw)) = (uint4){lw_[0], lw_[1], lw_[2], lw_[3]};
        }
        const float* e2g = (const float*)(ws + E2_OFF);
        for (int t = tid; t < NE; t += 256) e2s[t] = e2g[t];
    }
    asm volatile("s_waitcnt lgkmcnt(0)" ::: "memory");
    __builtin_amdgcn_sched_barrier(0);
    __builtin_amdgcn_s_barrier();
    __builtin_amdgcn_sched_barrier(0);

    // A fragments (hi, lo), 2 m-tiles per wave
    bf16x8 ah[2][2], al[2][2];
    #pragma unroll
    for (int mt = 0; mt < 2; ++mt) {
        int prow = (2 * wv + mt) * 16 + l15;
        int sw = (prow & 15) << 4;
        #pragma unroll
        for (int kh = 0; kh < 2; ++kh) {
            ah[mt][kh] = *(const bf16x8*)(xtb + ((prow * 256 + kh * 64 + l4 * 16) ^ sw));
            al[mt][kh] = *(const bf16x8*)(xtb + ((prow * 256 + 128 + kh * 64 + l4 * 16) ^ sw));
        }
    }
    asm volatile("s_waitcnt lgkmcnt(0)" ::: "memory");
    __builtin_amdgcn_sched_barrier(0);
    __builtin_amdgcn_s_barrier();      // all waves done with x tile; sbuf is now et dbuf
    __builtin_amdgcn_sched_barrier(0);

    // issue chunks 0,1 (each wave stages its 4KB quarter as 4 x 1KB)
    #pragma unroll
    for (int i = 0; i < 4; ++i)
        gload16(etw + 0 * 16384 + wv * 4096 + i * 1024 + lane * 16, &sbuf[0][wv * 4096 + i * 1024]);
    #pragma unroll
    for (int i = 0; i < 4; ++i)
        gload16(etw + 1 * 16384 + wv * 4096 + i * 1024 + lane * 16, &sbuf[1][wv * 4096 + i * 1024]);

    float minv[2][4], min2v[2][4];
    int   mini[2][4];
    #pragma unroll
    for (int mt = 0; mt < 2; ++mt)
        #pragma unroll
        for (int r = 0; r < 4; ++r) { minv[mt][r] = 3.4e38f; min2v[mt][r] = 3.4e38f; mini[mt][r] = 0; }

    for (int c = 0; c < 8; ++c) {
        if (c < 7) { asm volatile("s_waitcnt vmcnt(4)" ::: "memory"); }
        else       { asm volatile("s_waitcnt vmcnt(0)" ::: "memory"); }
        __builtin_amdgcn_sched_barrier(0);
        __builtin_amdgcn_s_barrier();          // chunk c resident for all waves
        __builtin_amdgcn_sched_barrier(0);
        const char* buf = &sbuf[c & 1][0];

        #pragma unroll
        for (int nt = 0; nt < 4; ++nt) {
            const int r = nt * 16 + l15;
            const int code = c * 64 + r;
            const int ro = r * 256 + l4 * 16;
            const int sw2 = (r & 15) << 4;
            bf16x8 bh0 = *(const bf16x8*)(buf + ((ro +   0) ^ sw2));
            bf16x8 bh1 = *(const bf16x8*)(buf + ((ro +  64) ^ sw2));
            bf16x8 bl0 = *(const bf16x8*)(buf + ((ro + 128) ^ sw2));
            bf16x8 bl1 = *(const bf16x8*)(buf + ((ro + 192) ^ sw2));
            float e2v = e2s[code];
            #pragma unroll
            for (int mt = 0; mt < 2; ++mt) {
                f32x4 acc = (f32x4){0.f, 0.f, 0.f, 0.f};
                acc = __builtin_amdgcn_mfma_f32_16x16x32_bf16(ah[mt][0], bh0, acc, 0, 0, 0);
                acc = __builtin_amdgcn_mfma_f32_16x16x32_bf16(ah[mt][1], bh1, acc, 0, 0, 0);
                acc = __builtin_amdgcn_mfma_f32_16x16x32_bf16(ah[mt][0], bl0, acc, 0, 0, 0);
                acc = __builtin_amdgcn_mfma_f32_16x16x32_bf16(ah[mt][1], bl1, acc, 0, 0, 0);
                acc = __builtin_amdgcn_mfma_f32_16x16x32_bf16(al[mt][0], bh0, acc, 0, 0, 0);
                acc = __builtin_amdgcn_mfma_f32_16x16x32_bf16(al[mt][1], bh1, acc, 0, 0, 0);
                #pragma unroll
                for (int r2 = 0; r2 < 4; ++r2) {
                    float d = __fmaf_rn(-2.f, acc[r2], e2v);
                    bool lt = d < minv[mt][r2];
                    min2v[mt][r2] = fminf(min2v[mt][r2], fmaxf(d, minv[mt][r2]));
                    minv[mt][r2] = lt ? d : minv[mt][r2];
                    mini[mt][r2] = lt ? code : mini[mt][r2];
                }
            }
        }

        if (c < 6) {
            asm volatile("s_waitcnt lgkmcnt(0)" ::: "memory");
            __builtin_amdgcn_sched_barrier(0);
            __builtin_amdgcn_s_barrier();      // all waves done reading buf (c&1); safe to overwrite
            __builtin_amdgcn_sched_barrier(0);
            const int cn = c + 2;
            #pragma unroll
            for (int i = 0; i < 4; ++i)
                gload16(etw + (size_t)cn * 16384 + wv * 4096 + i * 1024 + lane * 16,
                        &sbuf[c & 1][wv * 4096 + i * 1024]);
        }
    }

    // 16-lane argmin reduce with second-min tracking and first-index tie-break
    #pragma unroll
    for (int m = 1; m < 16; m <<= 1) {
        #pragma unroll
        for (int mt = 0; mt < 2; ++mt)
            #pragma unroll
            for (int r = 0; r < 4; ++r) {
                float ov  = __shfl_xor(minv[mt][r], m, 64);
                int   oi  = __shfl_xor(mini[mt][r], m, 64);
                float ov2 = __shfl_xor(min2v[mt][r], m, 64);
                bool sel = (ov < minv[mt][r]) || (ov == minv[mt][r] && oi < mini[mt][r]);
                float big = sel ? minv[mt][r] : ov;
                min2v[mt][r] = fminf(fminf(min2v[mt][r], ov2), big);
                minv[mt][r] = sel ? ov : minv[mt][r];
                mini[mt][r] = sel ? oi : mini[mt][r];
            }
    }
    if (l15 == 0) {
        #pragma unroll
        for (int mt = 0; mt < 2; ++mt)
            #pragma unroll
            for (int r = 0; r < 4; ++r) {
                int p = (2 * wv + mt) * 16 + l4 * 4 + r;
                idxs[p] = mini[mt][r];
                if (min2v[mt][r] - minv[mt][r] < EPS_MARGIN) {
                    int pos = atomicAdd(&nflag, 1);
                    flist[pos] = p;
                }
            }
    }
    __syncthreads();

    // exact recheck for near-tie pixels — bit-identical fp32 arithmetic
    const int nf = nflag;
    for (int f = 0; f < nf; ++f) {
        int p = flist[f];
        if (tid < CC) xp[tid] = xg[xbase + (size_t)tid * HWSZ + p];
        __syncthreads();
        float rr[8];
        #pragma unroll
        for (int u = 0; u < 8; ++u) { float v = xp[u]; rr[u] = __fmul_rn(v, v); }
        #pragma unroll
        for (int t2 = 1; t2 < 8; ++t2)
            #pragma unroll
            for (int u = 0; u < 8; ++u) { float v = xp[t2 * 8 + u]; rr[u] = __fadd_rn(rr[u], __fmul_rn(v, v)); }
        float f2 = __fadd_rn(__fadd_rn(__fadd_rn(rr[0], rr[1]), __fadd_rn(rr[2], rr[3])),
                             __fadd_rn(__fadd_rn(rr[4], rr[5]), __fadd_rn(rr[6], rr[7])));
        float best = 3.4e38f; int bidx = 0;
        const float* e2g = (const float*)(ws + E2_OFF);
        #pragma unroll
        for (int h = 0; h < 2; ++h) {
            int cgl = h * 256 + tid;
            float dot = 0.f;
            #pragma unroll 8
            for (int k = 0; k < CC; ++k) dot = __fmaf_rn(xp[k], eg[k * NE + cgl], dot);
            float d = __fadd_rn(__fmaf_rn(-2.f, dot, f2), e2g[cgl]);
            if (d < best) { best = d; bidx = cgl; }
        }
        #pragma unroll
        for (int m = 1; m < 64; m <<= 1) {
            float ov = __shfl_xor(best, m, 64);
            int   oi = __shfl_xor(bidx, m, 64);
            if (ov < best || (ov == best && oi < bidx)) { best = ov; bidx = oi; }
        }
        if (lane == 0) { redv[wv] = best; redi[wv] = bidx; }
        __syncthreads();
        if (tid == 0) {
            float bv = redv[0]; int bi = redi[0];
            #pragma unroll
            for (int w = 1; w < 4; ++w)
                if (redv[w] < bv || (redv[w] == bv && redi[w] < bi)) { bv = redv[w]; bi = redi[w]; }
            idxs[p] = bi;
        }
        __syncthreads();
    }

    // histogram: direct global atomics (128 per block)
    if (tid < PIXB) atomicAdd((unsigned int*)(ws + HIST_OFF) + idxs[tid], 1u);

    // epilogue: re-read x (L3-hot), recompute hi/lo split, out = x~ + (q - x~), sq loss
    float sq = 0.f;
    for (int t = tid; t < 8192; t += 256) {
        int cc = t >> 7, p = t & 127;
        float vr = xg[xbase + (size_t)cc * HWSZ + p];
        unsigned short hh = f2bf(vr);
        float hf = bf2f(hh);
        float lf = bf2f(f2bf(__fsub_rn(vr, hf)));
        float xv = __fadd_rn(hf, lf);
        int code = idxs[p];
        float q = eg[cc * NE + code];
        float d = __fsub_rn(q, xv);
        outg[xbase + (size_t)cc * HWSZ + p] = __fadd_rn(xv, d);
        sq = __fmaf_rn(d, d, sq);
    }
    #pragma unroll
    for (int m = 32; m >= 1; m >>= 1) sq += __shfl_down(sq, m, 64);
    if (lane == 0) wsum[wv] = sq;
    __syncthreads();
    if (tid == 0) atomicAdd((float*)(ws + BATCH_OFF) + bb, wsum[0] + wsum[1] + wsum[2] + wsum[3]);
}

// ---- finalize: diff[32] and perplexity ----
__global__ __launch_bounds__(512) void vq_fin(const char* __restrict__ ws, float* __restrict__ outg) {
    __shared__ float acc8[8];
    const int tid = threadIdx.x, lane = tid & 63, wv = tid >> 6;
    const unsigned int* ghist = (const unsigned int*)(ws + HIST_OFF);
    float p = (float)ghist[tid] * (1.f / (float)NPIX);
    float t = p * logf(p + 1e-10f);
    #pragma unroll
    for (int m = 32; m >= 1; m >>= 1) t += __shfl_down(t, m, 64);
    if (lane == 0) acc8[wv] = t;
    __syncthreads();
    if (tid < 32) outg[8388608 + tid] = ((const float*)(ws + BATCH_OFF))[tid] * (1.f / 262144.f);
    if (tid == 0) {
        float s = 0.f;
        #pragma unroll
        for (int u = 0; u < 8; ++u) s += acc8[u];
        outg[8388640] = expf(-s);
    }
}

extern "C" void kernel_launch(void* const* d_in, const int* in_sizes, int n_in,
                              void* d_out, int out_size, void* d_ws, size_t ws_size,
                              hipStream_t stream) {
    const float* xg = (const float*)d_in[0];
    const float* eg = (const float*)d_in[1];
    float* outg = (float*)d_out;
    char* ws = (char*)d_ws;
    vq_init<<<1, 512, 0, stream>>>(eg, ws);
    vq_main<<<NPIX / PIXB, 256, 0, stream>>>(xg, eg, outg, ws);
    vq_fin<<<1, 512, 0, stream>>>(ws, outg);
}

// Round 6
// 132.998 us; speedup vs baseline: 1.1480x; 1.1480x over previous
//
#include <hip/hip_runtime.h>

typedef __bf16 bf16x8 __attribute__((ext_vector_type(8)));
typedef float  f32x4  __attribute__((ext_vector_type(4)));

#define CC 64
#define HWSZ 4096
#define CHWSZ 262144
#define NE 512
#define NPIX 131072
#define PIXB 128
#define EPS_MARGIN 0.01f

#define ET_OFF 0            // 512 codes * 256 B (hi64|lo64 bf16), XOR-swizzled rows
#define E2_OFF 131072       // 512 * 4
#define HIST_OFF 133120     // 512 * 4
#define BATCH_OFF 135168    // 32 * 4

__device__ __forceinline__ float bf2f(unsigned short u) {
    unsigned int x = ((unsigned int)u) << 16;
    return __builtin_bit_cast(float, x);
}
__device__ __forceinline__ unsigned short f2bf(float f) {
    unsigned int x = __builtin_bit_cast(unsigned int, f);
    unsigned int r = x + 0x7fffu + ((x >> 16) & 1u);
    return (unsigned short)(r >> 16);
}
__device__ __forceinline__ void gload16(const void* g, void* l) {
    __builtin_amdgcn_global_load_lds(
        (const __attribute__((address_space(1))) unsigned int*)g,
        (__attribute__((address_space(3))) unsigned int*)l, 16, 0, 0);
}

// ---- init: exact e2[512]; embed^T hi/lo [code][hi64|lo64] bf16 PRE-SWIZZLED; zero hist/batch ----
__global__ __launch_bounds__(512) void vq_init(const float* __restrict__ eg, char* __restrict__ ws) {
    __shared__ float se[CC * 513];          // stride 513 kills transpose bank conflicts
    const int tid = threadIdx.x;
    for (int i = tid; i < CC * NE; i += 512) se[(i >> 9) * 513 + (i & 511)] = eg[i];
    __syncthreads();
    float s = 0.f;
    #pragma unroll 8
    for (int k = 0; k < CC; ++k) { float v = se[k * 513 + tid]; s = __fadd_rn(s, __fmul_rn(v, v)); }
    ((float*)(ws + E2_OFF))[tid] = s;
    char* et = ws + ET_OFF;
    #pragma unroll 4
    for (int it = 0; it < 64; ++it) {
        int idx = tid + it * 512;           // word index
        int n = idx >> 6;                   // code row
        int w = idx & 63;                   // word within row
        int kk2 = w << 1;                   // element pair col
        int k = kk2 & 63;
        float v0 = se[k * 513 + n], v1 = se[(k + 1) * 513 + n];
        unsigned short c0, c1;
        if (kk2 < 64) { c0 = f2bf(v0); c1 = f2bf(v1); }
        else {
            unsigned short h0 = f2bf(v0), h1 = f2bf(v1);
            c0 = f2bf(__fsub_rn(v0, bf2f(h0)));
            c1 = f2bf(__fsub_rn(v1, bf2f(h1)));
        }
        int b = (n * 256 + w * 4) ^ ((n & 15) << 4);   // row-local XOR swizzle
        *(unsigned int*)(et + b) = (unsigned int)c0 | ((unsigned int)c1 << 16);
    }
    ((unsigned int*)(ws + HIST_OFF))[tid] = 0u;
    if (tid < 32) ((float*)(ws + BATCH_OFF))[tid] = 0.f;
}

// ---- main: split-bf16 MFMA argmin, async dbuf et staging, LDS aliased ----
// NOTE: __launch_bounds__(256) ONLY — (256,4) capped VGPR at 64 and spilled
// (r4/r5: WRITE_SIZE 88-198MB of scratch traffic, both pipes <17%). 128 VGPR
// + 36KB LDS still reaches 4 blocks/CU.
__global__ __launch_bounds__(256) void vq_main(const float* __restrict__ xg,
                                               const float* __restrict__ eg,
                                               float* __restrict__ outg,
                                               char* __restrict__ ws) {
    __shared__ __align__(16) char sbuf[2][16384];  // phase 1: x tile [pixel][hi64|lo64]; phase 2: et dbuf
    __shared__ float e2s[NE];
    __shared__ int idxs[PIXB];
    __shared__ float wsum[4];
    __shared__ int nflag;
    __shared__ int flist[PIXB];
    __shared__ float xp[CC];
    __shared__ float redv[4];
    __shared__ int redi[4];

    const int tid  = threadIdx.x;
    const int lane = tid & 63;
    const int wv   = tid >> 6;
    const int l15  = lane & 15;
    const int l4   = lane >> 4;
    const int pix0 = blockIdx.x * PIXB;
    const int bb   = pix0 >> 12;
    const size_t xbase = (size_t)bb * CHWSZ + (pix0 & 4095);
    char* xtb = &sbuf[0][0];
    const char* etw = ws + ET_OFF;

    if (tid == 0) nflag = 0;

    // phase 1: stage x tile as bf16 hi/lo, swizzled; e2s
    {
        const int p = tid & 127, h = tid >> 7;
        const int sw = (p & 15) << 4;
        #pragma unroll
        for (int q = 0; q < 4; ++q) {
            int k0 = h * 32 + q * 8;
            float v[8];
            #pragma unroll
            for (int j = 0; j < 8; ++j) v[j] = xg[xbase + (size_t)(k0 + j) * HWSZ + p];
            unsigned int hw_[4], lw_[4];
            #pragma unroll
            for (int j = 0; j < 4; ++j) {
                unsigned short h0 = f2bf(v[2 * j]), h1 = f2bf(v[2 * j + 1]);
                unsigned short o0 = f2bf(__fsub_rn(v[2 * j], bf2f(h0)));
                unsigned short o1 = f2bf(__fsub_rn(v[2 * j + 1], bf2f(h1)));
                hw_[j] = (unsigned int)h0 | ((unsigned int)h1 << 16);
                lw_[j] = (unsigned int)o0 | ((unsigned int)o1 << 16);
            }
            *(uint4*)(xtb + ((p * 256 + 2 * k0) ^ sw)) = (uint4){hw_[0], hw_[1], hw_[2], hw_[3]};
            *(uint4*)(xtb + ((p * 256 + 128 + 2 * k0) ^ sw)) = (uint4){lw_[0], lw_[1], lw_[2], lw_[3]};
        }
        const float* e2g = (const float*)(ws + E2_OFF);
        for (int t = tid; t < NE; t += 256) e2s[t] = e2g[t];
    }
    asm volatile("s_waitcnt lgkmcnt(0)" ::: "memory");
    __builtin_amdgcn_sched_barrier(0);
    __builtin_amdgcn_s_barrier();
    __builtin_amdgcn_sched_barrier(0);

    // A fragments (hi, lo), 2 m-tiles per wave
    bf16x8 ah[2][2], al[2][2];
    #pragma unroll
    for (int mt = 0; mt < 2; ++mt) {
        int prow = (2 * wv + mt) * 16 + l15;
        int sw = (prow & 15) << 4;
        #pragma unroll
        for (int kh = 0; kh < 2; ++kh) {
            ah[mt][kh] = *(const bf16x8*)(xtb + ((prow * 256 + kh * 64 + l4 * 16) ^ sw));
            al[mt][kh] = *(const bf16x8*)(xtb + ((prow * 256 + 128 + kh * 64 + l4 * 16) ^ sw));
        }
    }
    asm volatile("s_waitcnt lgkmcnt(0)" ::: "memory");
    __builtin_amdgcn_sched_barrier(0);
    __builtin_amdgcn_s_barrier();      // all waves done with x tile; sbuf is now et dbuf
    __builtin_amdgcn_sched_barrier(0);

    // issue chunks 0,1 (each wave stages its 4KB quarter as 4 x 1KB)
    #pragma unroll
    for (int i = 0; i < 4; ++i)
        gload16(etw + 0 * 16384 + wv * 4096 + i * 1024 + lane * 16, &sbuf[0][wv * 4096 + i * 1024]);
    #pragma unroll
    for (int i = 0; i < 4; ++i)
        gload16(etw + 1 * 16384 + wv * 4096 + i * 1024 + lane * 16, &sbuf[1][wv * 4096 + i * 1024]);

    float minv[2][4], min2v[2][4];
    int   mini[2][4];
    #pragma unroll
    for (int mt = 0; mt < 2; ++mt)
        #pragma unroll
        for (int r = 0; r < 4; ++r) { minv[mt][r] = 3.4e38f; min2v[mt][r] = 3.4e38f; mini[mt][r] = 0; }

    for (int c = 0; c < 8; ++c) {
        if (c < 7) { asm volatile("s_waitcnt vmcnt(4)" ::: "memory"); }
        else       { asm volatile("s_waitcnt vmcnt(0)" ::: "memory"); }
        __builtin_amdgcn_sched_barrier(0);
        __builtin_amdgcn_s_barrier();          // chunk c resident for all waves
        __builtin_amdgcn_sched_barrier(0);
        const char* buf = &sbuf[c & 1][0];

        #pragma unroll
        for (int nt = 0; nt < 4; ++nt) {
            const int r = nt * 16 + l15;
            const int code = c * 64 + r;
            const int ro = r * 256 + l4 * 16;
            const int sw2 = (r & 15) << 4;
            bf16x8 bh0 = *(const bf16x8*)(buf + ((ro +   0) ^ sw2));
            bf16x8 bh1 = *(const bf16x8*)(buf + ((ro +  64) ^ sw2));
            bf16x8 bl0 = *(const bf16x8*)(buf + ((ro + 128) ^ sw2));
            bf16x8 bl1 = *(const bf16x8*)(buf + ((ro + 192) ^ sw2));
            float e2v = e2s[code];
            #pragma unroll
            for (int mt = 0; mt < 2; ++mt) {
                f32x4 acc = (f32x4){0.f, 0.f, 0.f, 0.f};
                acc = __builtin_amdgcn_mfma_f32_16x16x32_bf16(ah[mt][0], bh0, acc, 0, 0, 0);
                acc = __builtin_amdgcn_mfma_f32_16x16x32_bf16(ah[mt][1], bh1, acc, 0, 0, 0);
                acc = __builtin_amdgcn_mfma_f32_16x16x32_bf16(ah[mt][0], bl0, acc, 0, 0, 0);
                acc = __builtin_amdgcn_mfma_f32_16x16x32_bf16(ah[mt][1], bl1, acc, 0, 0, 0);
                acc = __builtin_amdgcn_mfma_f32_16x16x32_bf16(al[mt][0], bh0, acc, 0, 0, 0);
                acc = __builtin_amdgcn_mfma_f32_16x16x32_bf16(al[mt][1], bh1, acc, 0, 0, 0);
                #pragma unroll
                for (int r2 = 0; r2 < 4; ++r2) {
                    float d = __fmaf_rn(-2.f, acc[r2], e2v);
                    bool lt = d < minv[mt][r2];
                    min2v[mt][r2] = fminf(min2v[mt][r2], fmaxf(d, minv[mt][r2]));
                    minv[mt][r2] = lt ? d : minv[mt][r2];
                    mini[mt][r2] = lt ? code : mini[mt][r2];
                }
            }
        }

        if (c < 6) {
            asm volatile("s_waitcnt lgkmcnt(0)" ::: "memory");
            __builtin_amdgcn_sched_barrier(0);
            __builtin_amdgcn_s_barrier();      // all waves done reading buf (c&1); safe to overwrite
            __builtin_amdgcn_sched_barrier(0);
            const int cn = c + 2;
            #pragma unroll
            for (int i = 0; i < 4; ++i)
                gload16(etw + (size_t)cn * 16384 + wv * 4096 + i * 1024 + lane * 16,
                        &sbuf[c & 1][wv * 4096 + i * 1024]);
        }
    }

    // 16-lane argmin reduce with second-min tracking and first-index tie-break
    #pragma unroll
    for (int m = 1; m < 16; m <<= 1) {
        #pragma unroll
        for (int mt = 0; mt < 2; ++mt)
            #pragma unroll
            for (int r = 0; r < 4; ++r) {
                float ov  = __shfl_xor(minv[mt][r], m, 64);
                int   oi  = __shfl_xor(mini[mt][r], m, 64);
                float ov2 = __shfl_xor(min2v[mt][r], m, 64);
                bool sel = (ov < minv[mt][r]) || (ov == minv[mt][r] && oi < mini[mt][r]);
                float big = sel ? minv[mt][r] : ov;
                min2v[mt][r] = fminf(fminf(min2v[mt][r], ov2), big);
                minv[mt][r] = sel ? ov : minv[mt][r];
                mini[mt][r] = sel ? oi : mini[mt][r];
            }
    }
    if (l15 == 0) {
        #pragma unroll
        for (int mt = 0; mt < 2; ++mt)
            #pragma unroll
            for (int r = 0; r < 4; ++r) {
                int p = (2 * wv + mt) * 16 + l4 * 4 + r;
                idxs[p] = mini[mt][r];
                if (min2v[mt][r] - minv[mt][r] < EPS_MARGIN) {
                    int pos = atomicAdd(&nflag, 1);
                    flist[pos] = p;
                }
            }
    }
    __syncthreads();

    // exact recheck for near-tie pixels — bit-identical fp32 arithmetic
    const int nf = nflag;
    for (int f = 0; f < nf; ++f) {
        int p = flist[f];
        if (tid < CC) xp[tid] = xg[xbase + (size_t)tid * HWSZ + p];
        __syncthreads();
        float rr[8];
        #pragma unroll
        for (int u = 0; u < 8; ++u) { float v = xp[u]; rr[u] = __fmul_rn(v, v); }
        #pragma unroll
        for (int t2 = 1; t2 < 8; ++t2)
            #pragma unroll
            for (int u = 0; u < 8; ++u) { float v = xp[t2 * 8 + u]; rr[u] = __fadd_rn(rr[u], __fmul_rn(v, v)); }
        float f2 = __fadd_rn(__fadd_rn(__fadd_rn(rr[0], rr[1]), __fadd_rn(rr[2], rr[3])),
                             __fadd_rn(__fadd_rn(rr[4], rr[5]), __fadd_rn(rr[6], rr[7])));
        float best = 3.4e38f; int bidx = 0;
        const float* e2g = (const float*)(ws + E2_OFF);
        #pragma unroll
        for (int h = 0; h < 2; ++h) {
            int cgl = h * 256 + tid;
            float dot = 0.f;
            #pragma unroll 8
            for (int k = 0; k < CC; ++k) dot = __fmaf_rn(xp[k], eg[k * NE + cgl], dot);
            float d = __fadd_rn(__fmaf_rn(-2.f, dot, f2), e2g[cgl]);
            if (d < best) { best = d; bidx = cgl; }
        }
        #pragma unroll
        for (int m = 1; m < 64; m <<= 1) {
            float ov = __shfl_xor(best, m, 64);
            int   oi = __shfl_xor(bidx, m, 64);
            if (ov < best || (ov == best && oi < bidx)) { best = ov; bidx = oi; }
        }
        if (lane == 0) { redv[wv] = best; redi[wv] = bidx; }
        __syncthreads();
        if (tid == 0) {
            float bv = redv[0]; int bi = redi[0];
            #pragma unroll
            for (int w = 1; w < 4; ++w)
                if (redv[w] < bv || (redv[w] == bv && redi[w] < bi)) { bv = redv[w]; bi = redi[w]; }
            idxs[p] = bi;
        }
        __syncthreads();
    }

    // histogram: direct global atomics (128 per block)
    if (tid < PIXB) atomicAdd((unsigned int*)(ws + HIST_OFF) + idxs[tid], 1u);

    // epilogue (float4): re-read x, recompute hi/lo split, out = x~ + (q - x~), sq loss
    float sq = 0.f;
    for (int t = tid; t < 2048; t += 256) {
        int cc = t >> 5, p4 = (t & 31) << 2;
        float4 vr = *(const float4*)(xg + xbase + (size_t)cc * HWSZ + p4);
        float vv[4] = {vr.x, vr.y, vr.z, vr.w};
        float4 ov;
        float* ovp = &ov.x;
        #pragma unroll
        for (int j = 0; j < 4; ++j) {
            float hf = bf2f(f2bf(vv[j]));
            float lf = bf2f(f2bf(__fsub_rn(vv[j], hf)));
            float xv = __fadd_rn(hf, lf);
            float q = eg[cc * NE + idxs[p4 + j]];
            float d = __fsub_rn(q, xv);
            ovp[j] = __fadd_rn(xv, d);
            sq = __fmaf_rn(d, d, sq);
        }
        *(float4*)(outg + xbase + (size_t)cc * HWSZ + p4) = ov;
    }
    #pragma unroll
    for (int m = 32; m >= 1; m >>= 1) sq += __shfl_down(sq, m, 64);
    if (lane == 0) wsum[wv] = sq;
    __syncthreads();
    if (tid == 0) atomicAdd((float*)(ws + BATCH_OFF) + bb, wsum[0] + wsum[1] + wsum[2] + wsum[3]);
}

// ---- finalize: diff[32] and perplexity ----
__global__ __launch_bounds__(512) void vq_fin(const char* __restrict__ ws, float* __restrict__ outg) {
    __shared__ float acc8[8];
    const int tid = threadIdx.x, lane = tid & 63, wv = tid >> 6;
    const unsigned int* ghist = (const unsigned int*)(ws + HIST_OFF);
    float p = (float)ghist[tid] * (1.f / (float)NPIX);
    float t = p * logf(p + 1e-10f);
    #pragma unroll
    for (int m = 32; m >= 1; m >>= 1) t += __shfl_down(t, m, 64);
    if (lane == 0) acc8[wv] = t;
    __syncthreads();
    if (tid < 32) outg[8388608 + tid] = ((const float*)(ws + BATCH_OFF))[tid] * (1.f / 262144.f);
    if (tid == 0) {
        float s = 0.f;
        #pragma unroll
        for (int u = 0; u < 8; ++u) s += acc8[u];
        outg[8388640] = expf(-s);
    }
}

extern "C" void kernel_launch(void* const* d_in, const int* in_sizes, int n_in,
                              void* d_out, int out_size, void* d_ws, size_t ws_size,
                              hipStream_t stream) {
    const float* xg = (const float*)d_in[0];
    const float* eg = (const float*)d_in[1];
    float* outg = (float*)d_out;
    char* ws = (char*)d_ws;
    vq_init<<<1, 512, 0, stream>>>(eg, ws);
    vq_main<<<NPIX / PIXB, 256, 0, stream>>>(xg, eg, outg, ws);
    vq_fin<<<1, 512, 0, stream>>>(ws, outg);
}

// Round 7
// 102.667 us; speedup vs baseline: 1.4872x; 1.2954x over previous
//
#include <hip/hip_runtime.h>

typedef __bf16 bf16x8 __attribute__((ext_vector_type(8)));
typedef float  f32x4  __attribute__((ext_vector_type(4)));

#define CC 64
#define HWSZ 4096
#define CHWSZ 262144
#define NE 512
#define NPIX 131072
#define PIXB 128
#define EPS_MARGIN 0.01f
#define NSTRIPE 32

#define ET_OFF 0              // 512 codes * 256 B (hi64|lo64 bf16), XOR-swizzled rows
#define E2_OFF 131072         // 512 * 4
#define HIST_OFF 133120       // 32 stripes * 512 * 4 = 65536
#define BATCH_OFF 198656      // 32 * 4
#define IDX_OFF 198784        // 131072 * 2 (u16)

__device__ __forceinline__ float bf2f(unsigned short u) {
    unsigned int x = ((unsigned int)u) << 16;
    return __builtin_bit_cast(float, x);
}
__device__ __forceinline__ unsigned short f2bf(float f) {
    unsigned int x = __builtin_bit_cast(unsigned int, f);
    unsigned int r = x + 0x7fffu + ((x >> 16) & 1u);
    return (unsigned short)(r >> 16);
}
__device__ __forceinline__ void gload16(const void* g, void* l) {
    __builtin_amdgcn_global_load_lds(
        (const __attribute__((address_space(1))) unsigned int*)g,
        (__attribute__((address_space(3))) unsigned int*)l, 16, 0, 0);
}

// ---- init: exact e2[512]; embed^T hi/lo [code][hi64|lo64] bf16 pre-swizzled; zero hist/batch ----
__global__ __launch_bounds__(512) void vq_init(const float* __restrict__ eg, char* __restrict__ ws) {
    __shared__ float se[CC * 513];
    const int tid = threadIdx.x;
    for (int i = tid; i < CC * NE; i += 512) se[(i >> 9) * 513 + (i & 511)] = eg[i];
    __syncthreads();
    float s = 0.f;
    #pragma unroll 8
    for (int k = 0; k < CC; ++k) { float v = se[k * 513 + tid]; s = __fadd_rn(s, __fmul_rn(v, v)); }
    ((float*)(ws + E2_OFF))[tid] = s;
    char* et = ws + ET_OFF;
    #pragma unroll 4
    for (int it = 0; it < 64; ++it) {
        int idx = tid + it * 512;
        int n = idx >> 6, w = idx & 63;
        int kk2 = w << 1, k = kk2 & 63;
        float v0 = se[k * 513 + n], v1 = se[(k + 1) * 513 + n];
        unsigned short c0, c1;
        if (kk2 < 64) { c0 = f2bf(v0); c1 = f2bf(v1); }
        else {
            unsigned short h0 = f2bf(v0), h1 = f2bf(v1);
            c0 = f2bf(__fsub_rn(v0, bf2f(h0)));
            c1 = f2bf(__fsub_rn(v1, bf2f(h1)));
        }
        int b = (n * 256 + w * 4) ^ ((n & 15) << 4);
        *(unsigned int*)(et + b) = (unsigned int)c0 | ((unsigned int)c1 << 16);
    }
    unsigned int* h32 = (unsigned int*)(ws + HIST_OFF);
    for (int i = tid; i < NSTRIPE * NE; i += 512) h32[i] = 0u;
    if (tid < 32) ((float*)(ws + BATCH_OFF))[tid] = 0.f;
}

// ---- K1: split-bf16 MFMA argmin -> idx[] + striped hist ----
__global__ __launch_bounds__(256) void vq_argmin(const float* __restrict__ xg,
                                                 const float* __restrict__ eg,
                                                 char* __restrict__ ws) {
    __shared__ __align__(16) char sbuf[2][16384];  // phase 1: x tile; phase 2: et dbuf
    __shared__ float e2s[NE];
    __shared__ int idxs[PIXB];
    __shared__ int nflag;
    __shared__ int flist[PIXB];
    __shared__ float xp[CC];
    __shared__ float redv[4];
    __shared__ int redi[4];

    const int tid  = threadIdx.x;
    const int lane = tid & 63;
    const int wv   = tid >> 6;
    const int l15  = lane & 15;
    const int l4   = lane >> 4;
    const int pix0 = blockIdx.x * PIXB;
    const int bb   = pix0 >> 12;
    const size_t xbase = (size_t)bb * CHWSZ + (pix0 & 4095);
    char* xtb = &sbuf[0][0];
    const char* etw = ws + ET_OFF;

    if (tid == 0) nflag = 0;

    // stage x tile as bf16 hi/lo, swizzled; e2s
    {
        const int p = tid & 127, h = tid >> 7;
        const int sw = (p & 15) << 4;
        #pragma unroll
        for (int q = 0; q < 4; ++q) {
            int k0 = h * 32 + q * 8;
            float v[8];
            #pragma unroll
            for (int j = 0; j < 8; ++j) v[j] = xg[xbase + (size_t)(k0 + j) * HWSZ + p];
            unsigned int hw_[4], lw_[4];
            #pragma unroll
            for (int j = 0; j < 4; ++j) {
                unsigned short h0 = f2bf(v[2 * j]), h1 = f2bf(v[2 * j + 1]);
                unsigned short o0 = f2bf(__fsub_rn(v[2 * j], bf2f(h0)));
                unsigned short o1 = f2bf(__fsub_rn(v[2 * j + 1], bf2f(h1)));
                hw_[j] = (unsigned int)h0 | ((unsigned int)h1 << 16);
                lw_[j] = (unsigned int)o0 | ((unsigned int)o1 << 16);
            }
            *(uint4*)(xtb + ((p * 256 + 2 * k0) ^ sw)) = (uint4){hw_[0], hw_[1], hw_[2], hw_[3]};
            *(uint4*)(xtb + ((p * 256 + 128 + 2 * k0) ^ sw)) = (uint4){lw_[0], lw_[1], lw_[2], lw_[3]};
        }
        const float* e2g = (const float*)(ws + E2_OFF);
        for (int t = tid; t < NE; t += 256) e2s[t] = e2g[t];
    }
    asm volatile("s_waitcnt lgkmcnt(0)" ::: "memory");
    __builtin_amdgcn_sched_barrier(0);
    __builtin_amdgcn_s_barrier();
    __builtin_amdgcn_sched_barrier(0);

    bf16x8 ah[2][2], al[2][2];
    #pragma unroll
    for (int mt = 0; mt < 2; ++mt) {
        int prow = (2 * wv + mt) * 16 + l15;
        int sw = (prow & 15) << 4;
        #pragma unroll
        for (int kh = 0; kh < 2; ++kh) {
            ah[mt][kh] = *(const bf16x8*)(xtb + ((prow * 256 + kh * 64 + l4 * 16) ^ sw));
            al[mt][kh] = *(const bf16x8*)(xtb + ((prow * 256 + 128 + kh * 64 + l4 * 16) ^ sw));
        }
    }
    asm volatile("s_waitcnt lgkmcnt(0)" ::: "memory");
    __builtin_amdgcn_sched_barrier(0);
    __builtin_amdgcn_s_barrier();      // x tile consumed; sbuf becomes et dbuf
    __builtin_amdgcn_sched_barrier(0);

    #pragma unroll
    for (int i = 0; i < 4; ++i)
        gload16(etw + 0 * 16384 + wv * 4096 + i * 1024 + lane * 16, &sbuf[0][wv * 4096 + i * 1024]);
    #pragma unroll
    for (int i = 0; i < 4; ++i)
        gload16(etw + 1 * 16384 + wv * 4096 + i * 1024 + lane * 16, &sbuf[1][wv * 4096 + i * 1024]);

    float minv[2][4], min2v[2][4];
    int   mini[2][4];
    #pragma unroll
    for (int mt = 0; mt < 2; ++mt)
        #pragma unroll
        for (int r = 0; r < 4; ++r) { minv[mt][r] = 3.4e38f; min2v[mt][r] = 3.4e38f; mini[mt][r] = 0; }

    for (int c = 0; c < 8; ++c) {
        if (c < 7) { asm volatile("s_waitcnt vmcnt(4)" ::: "memory"); }
        else       { asm volatile("s_waitcnt vmcnt(0)" ::: "memory"); }
        __builtin_amdgcn_sched_barrier(0);
        __builtin_amdgcn_s_barrier();
        __builtin_amdgcn_sched_barrier(0);
        const char* buf = &sbuf[c & 1][0];

        #pragma unroll
        for (int nt = 0; nt < 4; ++nt) {
            const int r = nt * 16 + l15;
            const int code = c * 64 + r;
            const int ro = r * 256 + l4 * 16;
            const int sw2 = (r & 15) << 4;
            bf16x8 bh0 = *(const bf16x8*)(buf + ((ro +   0) ^ sw2));
            bf16x8 bh1 = *(const bf16x8*)(buf + ((ro +  64) ^ sw2));
            bf16x8 bl0 = *(const bf16x8*)(buf + ((ro + 128) ^ sw2));
            bf16x8 bl1 = *(const bf16x8*)(buf + ((ro + 192) ^ sw2));
            float e2v = e2s[code];
            #pragma unroll
            for (int mt = 0; mt < 2; ++mt) {
                f32x4 acc = (f32x4){0.f, 0.f, 0.f, 0.f};
                acc = __builtin_amdgcn_mfma_f32_16x16x32_bf16(ah[mt][0], bh0, acc, 0, 0, 0);
                acc = __builtin_amdgcn_mfma_f32_16x16x32_bf16(ah[mt][1], bh1, acc, 0, 0, 0);
                acc = __builtin_amdgcn_mfma_f32_16x16x32_bf16(ah[mt][0], bl0, acc, 0, 0, 0);
                acc = __builtin_amdgcn_mfma_f32_16x16x32_bf16(ah[mt][1], bl1, acc, 0, 0, 0);
                acc = __builtin_amdgcn_mfma_f32_16x16x32_bf16(al[mt][0], bh0, acc, 0, 0, 0);
                acc = __builtin_amdgcn_mfma_f32_16x16x32_bf16(al[mt][1], bh1, acc, 0, 0, 0);
                #pragma unroll
                for (int r2 = 0; r2 < 4; ++r2) {
                    float d = __fmaf_rn(-2.f, acc[r2], e2v);
                    bool lt = d < minv[mt][r2];
                    min2v[mt][r2] = fminf(min2v[mt][r2], fmaxf(d, minv[mt][r2]));
                    minv[mt][r2] = lt ? d : minv[mt][r2];
                    mini[mt][r2] = lt ? code : mini[mt][r2];
                }
            }
        }

        if (c < 6) {
            asm volatile("s_waitcnt lgkmcnt(0)" ::: "memory");
            __builtin_amdgcn_sched_barrier(0);
            __builtin_amdgcn_s_barrier();
            __builtin_amdgcn_sched_barrier(0);
            const int cn = c + 2;
            #pragma unroll
            for (int i = 0; i < 4; ++i)
                gload16(etw + (size_t)cn * 16384 + wv * 4096 + i * 1024 + lane * 16,
                        &sbuf[c & 1][wv * 4096 + i * 1024]);
        }
    }

    #pragma unroll
    for (int m = 1; m < 16; m <<= 1) {
        #pragma unroll
        for (int mt = 0; mt < 2; ++mt)
            #pragma unroll
            for (int r = 0; r < 4; ++r) {
                float ov  = __shfl_xor(minv[mt][r], m, 64);
                int   oi  = __shfl_xor(mini[mt][r], m, 64);
                float ov2 = __shfl_xor(min2v[mt][r], m, 64);
                bool sel = (ov < minv[mt][r]) || (ov == minv[mt][r] && oi < mini[mt][r]);
                float big = sel ? minv[mt][r] : ov;
                min2v[mt][r] = fminf(fminf(min2v[mt][r], ov2), big);
                minv[mt][r] = sel ? ov : minv[mt][r];
                mini[mt][r] = sel ? oi : mini[mt][r];
            }
    }
    if (l15 == 0) {
        #pragma unroll
        for (int mt = 0; mt < 2; ++mt)
            #pragma unroll
            for (int r = 0; r < 4; ++r) {
                int p = (2 * wv + mt) * 16 + l4 * 4 + r;
                idxs[p] = mini[mt][r];
                if (min2v[mt][r] - minv[mt][r] < EPS_MARGIN) {
                    int pos = atomicAdd(&nflag, 1);
                    flist[pos] = p;
                }
            }
    }
    __syncthreads();

    // exact recheck for near-tie pixels (rare) — bit-identical fp32 arithmetic
    const int nf = nflag;
    for (int f = 0; f < nf; ++f) {
        int p = flist[f];
        if (tid < CC) xp[tid] = xg[xbase + (size_t)tid * HWSZ + p];
        __syncthreads();
        float rr[8];
        #pragma unroll
        for (int u = 0; u < 8; ++u) { float v = xp[u]; rr[u] = __fmul_rn(v, v); }
        #pragma unroll
        for (int t2 = 1; t2 < 8; ++t2)
            #pragma unroll
            for (int u = 0; u < 8; ++u) { float v = xp[t2 * 8 + u]; rr[u] = __fadd_rn(rr[u], __fmul_rn(v, v)); }
        float f2 = __fadd_rn(__fadd_rn(__fadd_rn(rr[0], rr[1]), __fadd_rn(rr[2], rr[3])),
                             __fadd_rn(__fadd_rn(rr[4], rr[5]), __fadd_rn(rr[6], rr[7])));
        float best = 3.4e38f; int bidx = 0;
        const float* e2g = (const float*)(ws + E2_OFF);
        #pragma unroll
        for (int h = 0; h < 2; ++h) {
            int cgl = h * 256 + tid;
            float dot = 0.f;
            #pragma unroll 8
            for (int k = 0; k < CC; ++k) dot = __fmaf_rn(xp[k], eg[k * NE + cgl], dot);
            float d = __fadd_rn(__fmaf_rn(-2.f, dot, f2), e2g[cgl]);
            if (d < best) { best = d; bidx = cgl; }
        }
        #pragma unroll
        for (int m = 1; m < 64; m <<= 1) {
            float ov = __shfl_xor(best, m, 64);
            int   oi = __shfl_xor(bidx, m, 64);
            if (ov < best || (ov == best && oi < bidx)) { best = ov; bidx = oi; }
        }
        if (lane == 0) { redv[wv] = best; redi[wv] = bidx; }
        __syncthreads();
        if (tid == 0) {
            float bv = redv[0]; int bi = redi[0];
            #pragma unroll
            for (int w = 1; w < 4; ++w)
                if (redv[w] < bv || (redv[w] == bv && redi[w] < bi)) { bv = redv[w]; bi = redi[w]; }
            idxs[p] = bi;
        }
        __syncthreads();
    }

    // outputs: idx[] to ws + striped hist atomics (stripe by block -> 32x less line contention)
    if (tid < PIXB) {
        int code = idxs[tid];
        ((unsigned short*)(ws + IDX_OFF))[pix0 + tid] = (unsigned short)code;
        atomicAdd((unsigned int*)(ws + HIST_OFF) + (blockIdx.x & (NSTRIPE - 1)) * NE + code, 1u);
    }
}

// ---- K2: streaming apply — block = one (batch, channel) plane of 4096 pixels ----
__global__ __launch_bounds__(256) void vq_apply(const float* __restrict__ xg,
                                                const float* __restrict__ eg,
                                                float* __restrict__ outg,
                                                char* __restrict__ ws) {
    __shared__ float wsum[4];
    const int tid = threadIdx.x, lane = tid & 63, wv = tid >> 6;
    const int bb = blockIdx.x >> 6;          // batch
    const int cc = blockIdx.x & 63;          // channel
    const size_t base = (size_t)bb * CHWSZ + (size_t)cc * HWSZ;
    const unsigned short* idxg = (const unsigned short*)(ws + IDX_OFF) + bb * 4096;
    const float* erow = eg + cc * NE;

    float sq = 0.f;
    #pragma unroll
    for (int it = 0; it < 4; ++it) {
        int p4 = (it * 256 + tid) * 4;
        float4 vr = *(const float4*)(xg + base + p4);
        ushort4 iv = *(const ushort4*)(idxg + p4);
        float q0 = erow[iv.x], q1 = erow[iv.y], q2 = erow[iv.z], q3 = erow[iv.w];
        float vv[4] = {vr.x, vr.y, vr.z, vr.w};
        float qq[4] = {q0, q1, q2, q3};
        float4 ov;
        float* ovp = &ov.x;
        #pragma unroll
        for (int j = 0; j < 4; ++j) {
            float d = __fsub_rn(qq[j], vv[j]);          // exact ref arithmetic
            ovp[j] = __fadd_rn(vv[j], d);
            sq = __fmaf_rn(d, d, sq);
        }
        *(float4*)(outg + base + p4) = ov;
    }
    #pragma unroll
    for (int m = 32; m >= 1; m >>= 1) sq += __shfl_down(sq, m, 64);
    if (lane == 0) wsum[wv] = sq;
    __syncthreads();
    if (tid == 0) atomicAdd((float*)(ws + BATCH_OFF) + bb, wsum[0] + wsum[1] + wsum[2] + wsum[3]);
}

// ---- finalize: sum hist stripes, diff[32], perplexity ----
__global__ __launch_bounds__(512) void vq_fin(const char* __restrict__ ws, float* __restrict__ outg) {
    __shared__ float acc8[8];
    const int tid = threadIdx.x, lane = tid & 63, wv = tid >> 6;
    const unsigned int* h32 = (const unsigned int*)(ws + HIST_OFF);
    unsigned int h = 0;
    #pragma unroll
    for (int s = 0; s < NSTRIPE; ++s) h += h32[s * NE + tid];
    float p = (float)h * (1.f / (float)NPIX);
    float t = p * logf(p + 1e-10f);
    #pragma unroll
    for (int m = 32; m >= 1; m >>= 1) t += __shfl_down(t, m, 64);
    if (lane == 0) acc8[wv] = t;
    __syncthreads();
    if (tid < 32) outg[8388608 + tid] = ((const float*)(ws + BATCH_OFF))[tid] * (1.f / 262144.f);
    if (tid == 0) {
        float s = 0.f;
        #pragma unroll
        for (int u = 0; u < 8; ++u) s += acc8[u];
        outg[8388640] = expf(-s);
    }
}

extern "C" void kernel_launch(void* const* d_in, const int* in_sizes, int n_in,
                              void* d_out, int out_size, void* d_ws, size_t ws_size,
                              hipStream_t stream) {
    const float* xg = (const float*)d_in[0];
    const float* eg = (const float*)d_in[1];
    float* outg = (float*)d_out;
    char* ws = (char*)d_ws;
    vq_init<<<1, 512, 0, stream>>>(eg, ws);
    vq_argmin<<<NPIX / PIXB, 256, 0, stream>>>(xg, eg, ws);
    vq_apply<<<32 * 64, 256, 0, stream>>>(xg, eg, outg, ws);
    vq_fin<<<1, 512, 0, stream>>>(ws, outg);
}